// Round 2
// baseline (2453.310 us; speedup 1.0000x reference)
//
#include <hip/hip_runtime.h>

typedef unsigned short u16;
typedef unsigned int u32;
typedef __attribute__((ext_vector_type(8))) short s16x8;
typedef __attribute__((ext_vector_type(4))) float f32x4;

__device__ inline u16 f2bf(float f){
    u32 u = __float_as_uint(f);
    u32 r = (u + 0x7fffu + ((u >> 16) & 1u)) >> 16;
    return (u16)r;
}
__device__ inline float bf2f(u16 h){
    return __uint_as_float(((u32)h) << 16);
}

#define GLOAD_LDS16(g, l) __builtin_amdgcn_global_load_lds( \
    (__attribute__((address_space(1))) void*)(void*)(g),    \
    (__attribute__((address_space(3))) void*)(l), 16, 0, 0)

// ---------------------------------------------------------------------------
// Generic NT GEMM: C(M,N) = A(M,K) * B(N,K)^T, bf16 inputs, fp32 accum.
// 128x128 tile, BK=64, 4 waves (2x2), each wave 64x64 via 4x4 mfma 16x16x32.
// EPI: 0 = store bf16 (xz)
//      1 = store fp32 (x_dbl, ldc=N) + bf16 dtin for col<64
//      2 = softplus(acc + aux0[col]) -> bf16 Cb[(b*2048+col)*4096 + t]
//      3 = acc + aux0[col]*aux1[row*N+col] -> fp32 Cf (final output)
// ---------------------------------------------------------------------------
template<int EPI>
__global__ __launch_bounds__(256) void gemm_nt(
    const u16* __restrict__ A, const u16* __restrict__ B,
    int M, int N, int K,
    float* __restrict__ Cf, u16* __restrict__ Cb,
    const float* __restrict__ aux0, const float* __restrict__ aux1)
{
    constexpr int BK = 64;
    __shared__ u16 As[128 * BK];
    __shared__ u16 Bs[128 * BK];
    const int tid  = threadIdx.x;
    const int lane = tid & 63, wave = tid >> 6;
    const int wr = wave >> 1, wc = wave & 1;
    const int bm = blockIdx.x, bn = blockIdx.y;
    const int l16 = lane & 15, lg = lane >> 4;

    const u16* Ab = A + (size_t)bm * 128 * K;
    const u16* Bb = B + (size_t)bn * 128 * K;

    f32x4 acc[4][4] = {};

    for (int kt = 0; kt < K; kt += BK) {
        #pragma unroll
        for (int p = 0; p < 4; p++) {
            int flat = (p * 256 + tid) * 8;
            int r = flat >> 6, c = flat & 63;
            GLOAD_LDS16(Ab + (size_t)r * K + kt + c, As + flat);
        }
        #pragma unroll
        for (int p = 0; p < 4; p++) {
            int flat = (p * 256 + tid) * 8;
            int r = flat >> 6, c = flat & 63;
            GLOAD_LDS16(Bb + (size_t)r * K + kt + c, Bs + flat);
        }
        asm volatile("s_waitcnt vmcnt(0)" ::: "memory");
        __syncthreads();
        #pragma unroll
        for (int kk = 0; kk < 2; kk++) {
            s16x8 a[4], b[4];
            #pragma unroll
            for (int m = 0; m < 4; m++)
                a[m] = *(const s16x8*)&As[(wr * 64 + m * 16 + l16) * BK + kk * 32 + lg * 8];
            #pragma unroll
            for (int n = 0; n < 4; n++)
                b[n] = *(const s16x8*)&Bs[(wc * 64 + n * 16 + l16) * BK + kk * 32 + lg * 8];
            #pragma unroll
            for (int m = 0; m < 4; m++)
                #pragma unroll
                for (int n = 0; n < 4; n++)
                    acc[m][n] = __builtin_amdgcn_mfma_f32_16x16x32_bf16(a[m], b[n], acc[m][n], 0, 0, 0);
        }
        __syncthreads();
    }

    const int row0 = bm * 128 + wr * 64 + lg * 4;
    const int col0 = bn * 128 + wc * 64 + l16;
    #pragma unroll
    for (int m = 0; m < 4; m++) {
        #pragma unroll
        for (int n = 0; n < 4; n++) {
            const int col = col0 + n * 16;
            #pragma unroll
            for (int r = 0; r < 4; r++) {
                const int row = row0 + m * 16 + r;
                float v = acc[m][n][r];
                if (EPI == 0) {
                    Cb[(size_t)row * N + col] = f2bf(v);
                } else if (EPI == 1) {
                    Cf[(size_t)row * N + col] = v;
                    if (col < 64) Cb[(size_t)row * 64 + col] = f2bf(v);
                } else if (EPI == 2) {
                    float t2 = v + aux0[col];
                    float sp = (t2 > 20.f) ? t2 : log1pf(__expf(t2));
                    int bb = row >> 12, tt = row & 4095;
                    Cb[((size_t)bb * 2048 + col) * 4096 + tt] = f2bf(sp);
                } else {
                    float o = v + aux0[col] * aux1[(size_t)row * N + col];
                    Cf[(size_t)row * N + col] = o;
                }
            }
        }
    }
}

// ---------------------------------------------------------------------------
// fp32 -> bf16 conversion (n divisible by 4)
// ---------------------------------------------------------------------------
__global__ void cvt_f32_bf16(const float* __restrict__ in, u16* __restrict__ out, int n)
{
    int i = (blockIdx.x * 256 + threadIdx.x) * 4;
    if (i < n) {
        f32x4 v = *(const f32x4*)(in + i);
        ushort4 o;
        o.x = f2bf(v[0]); o.y = f2bf(v[1]); o.z = f2bf(v[2]); o.w = f2bf(v[3]);
        *(ushort4*)(out + i) = o;
    }
}

// x_proj_w (96,2048) -> bf16 padded to (128,2048), rows 96..127 = 0
__global__ void cvt_pad_xproj(const float* __restrict__ in, u16* __restrict__ out)
{
    int i = blockIdx.x * 256 + threadIdx.x;  // 0..262143
    int row = i >> 11, col = i & 2047;
    float v = (row < 96) ? in[row * 2048 + col] : 0.f;
    out[i] = f2bf(v);
}

// ---------------------------------------------------------------------------
// Depthwise causal conv (D_CONV=4) + bias + SiLU.
// Reads x part of xz (bf16, (8192,4096) rows, cols 0..2047).
// Writes x_conv (token-major bf16) and x_t (channel-major bf16, LDS transpose).
// grid: (L/64, D_INNER/64, B), block 256.
// ---------------------------------------------------------------------------
__global__ __launch_bounds__(256) void conv_silu(
    const u16* __restrict__ xz, const float* __restrict__ cw,
    const float* __restrict__ cb, u16* __restrict__ xc,
    u16* __restrict__ x_t)
{
    __shared__ float tile[64][65];
    const int t0 = blockIdx.x * 64, d0 = blockIdx.y * 64, b = blockIdx.z;
    const int tid = threadIdx.x;
    const int dc = tid & 63, tr = tid >> 6;
    const int d = d0 + dc;
    const float w0 = cw[d * 4 + 0], w1 = cw[d * 4 + 1];
    const float w2 = cw[d * 4 + 2], w3 = cw[d * 4 + 3];
    const float bias = cb[d];
    #pragma unroll
    for (int p = 0; p < 16; p++) {
        int t = t0 + p * 4 + tr;
        int tok = b * 4096 + t;
        float s = bias;
        if (t >= 3) s += bf2f(xz[(size_t)(tok - 3) * 4096 + d]) * w0;
        if (t >= 2) s += bf2f(xz[(size_t)(tok - 2) * 4096 + d]) * w1;
        if (t >= 1) s += bf2f(xz[(size_t)(tok - 1) * 4096 + d]) * w2;
        s += bf2f(xz[(size_t)tok * 4096 + d]) * w3;
        float v = s / (1.f + __expf(-s));  // silu
        xc[(size_t)tok * 2048 + d] = f2bf(v);
        tile[p * 4 + tr][dc] = v;
    }
    __syncthreads();
    #pragma unroll
    for (int p = 0; p < 16; p++) {
        int dl = p * 4 + tr;
        float v = tile[dc][dl];
        x_t[((size_t)b * 2048 + d0 + dl) * 4096 + t0 + dc] = f2bf(v);
    }
}

// ---------------------------------------------------------------------------
// Selective scan, fused with (y + x*D_in)*silu(z) epilogue -> yy bf16.
// One 16-lane group per (b,d) channel; lane n holds state n.
// h_t[n] = exp(dt*A[d][n]) * h_{t-1}[n] + dt*x*B[t][n];  y_t = sum_n h_t[n]*C[t][n]
// grid: 256 blocks x 256 threads = 65536 threads = 4096 channels.
// ---------------------------------------------------------------------------
__global__ __launch_bounds__(256) void scan_fused(
    const u16* __restrict__ dt_t, const u16* __restrict__ x_t,
    const float* __restrict__ x_dbl, const float* __restrict__ A_log,
    const u16* __restrict__ xz, const float* __restrict__ D_in,
    u16* __restrict__ yy)
{
    const int gid = blockIdx.x * 256 + threadIdx.x;
    const int n = gid & 15;
    const int ch = gid >> 4;          // 0..4095
    const int d = ch & 2047, b = ch >> 11;
    const float Adn = -__expf(A_log[d * 16 + n]);
    const float Dd = D_in[d];
    const u16* dtp = dt_t + ((size_t)b * 2048 + d) * 4096;
    const u16* xp  = x_t  + ((size_t)b * 2048 + d) * 4096;
    const float* xdB = x_dbl + (size_t)b * 4096 * 128 + 64 + n;
    const float* xdC = xdB + 16;
    const u16* zp = xz + (size_t)b * 4096 * 4096 + 2048 + d;
    u16* yp = yy + (size_t)b * 4096 * 2048 + d;

    float h = 0.f;
    s16x8 dtv8 = *(const s16x8*)(dtp);
    s16x8 xv8  = *(const s16x8*)(xp);
    float Bz[8], Cz[8];
    #pragma unroll
    for (int j = 0; j < 8; j++) { Bz[j] = xdB[(size_t)j * 128]; Cz[j] = xdC[(size_t)j * 128]; }

    for (int t0 = 0; t0 < 4096; t0 += 8) {
        s16x8 ndt = {}, nx = {};
        float nB[8] = {}, nC[8] = {};
        int tn = t0 + 8;
        if (tn < 4096) {
            ndt = *(const s16x8*)(dtp + tn);
            nx  = *(const s16x8*)(xp + tn);
            #pragma unroll
            for (int j = 0; j < 8; j++) {
                nB[j] = xdB[(size_t)(tn + j) * 128];
                nC[j] = xdC[(size_t)(tn + j) * 128];
            }
        }
        #pragma unroll
        for (int j = 0; j < 8; j++) {
            float dtv = bf2f((u16)dtv8[j]);
            float xv  = bf2f((u16)xv8[j]);
            float a = __expf(dtv * Adn);
            h = fmaf(a, h, dtv * xv * Bz[j]);
            float r = h * Cz[j];
            r += __shfl_xor(r, 1);
            r += __shfl_xor(r, 2);
            r += __shfl_xor(r, 4);
            r += __shfl_xor(r, 8);
            if (n == 0) {
                int t = t0 + j;
                float zv = bf2f(zp[(size_t)t * 4096]);
                float val = (r + xv * Dd) * (zv / (1.f + __expf(-zv)));
                yp[(size_t)t * 2048] = f2bf(val);
            }
        }
        dtv8 = ndt; xv8 = nx;
        #pragma unroll
        for (int j = 0; j < 8; j++) { Bz[j] = nB[j]; Cz[j] = nC[j]; }
    }
}

// ---------------------------------------------------------------------------
extern "C" void kernel_launch(void* const* d_in, const int* in_sizes, int n_in,
                              void* d_out, int out_size, void* d_ws, size_t ws_size,
                              hipStream_t stream)
{
    const float* u       = (const float*)d_in[0];   // (2,4096,1024)
    const float* Wi      = (const float*)d_in[1];   // (4096,1024)
    const float* conv_w  = (const float*)d_in[2];   // (2048,4)
    const float* conv_b  = (const float*)d_in[3];   // (2048)
    const float* Wx      = (const float*)d_in[4];   // (96,2048)
    const float* Wdt     = (const float*)d_in[5];   // (2048,64)
    const float* dt_bias = (const float*)d_in[6];   // (2048)
    const float* A_log   = (const float*)d_in[7];   // (2048,16)
    const float* D_in_   = (const float*)d_in[8];   // (2048)
    const float* Wo      = (const float*)d_in[9];   // (1024,2048)
    const float* D_skip  = (const float*)d_in[10];  // (1024)
    float* out = (float*)d_out;
    (void)in_sizes; (void)n_in; (void)out_size;

    // ---- workspace layout with live-range aliasing (~170 MB total) ----
    const size_t MB = 1u << 20;
    char* ws = (char*)d_ws;
    // S0: xz bf16 (8192 x 4096)                  [in_proj .. scan]
    u16* xz = (u16*)(ws + 0);
    // S1: x_t bf16 (2,2048,4096) channel-major   [conv .. scan]
    u16* x_t = (u16*)(ws + 64 * MB);
    // S2: xc bf16 (8192 x 2048) [conv .. x_proj]  ALIAS dt_t bf16 (2,2048,4096) [dt_proj .. scan]
    u16* xc   = (u16*)(ws + 96 * MB);
    u16* dt_t = (u16*)(ws + 96 * MB);
    // S3: u_bf(16MB)+Wi_bf(8MB) [cvt .. in_proj]  ALIAS yy bf16 (8192 x 2048) [scan .. out_proj]
    u16* u_bf  = (u16*)(ws + 128 * MB);
    u16* Wi_bf = (u16*)(ws + 144 * MB);
    u16* yybuf = (u16*)(ws + 128 * MB);
    // S4: x_dbl fp32 (8192 x 128)
    float* x_dbl = (float*)(ws + 160 * MB);
    // S5: dtin bf16 (8192 x 64)
    u16* dtin = (u16*)(ws + 164 * MB);
    // S6: Wo_bf (1024 x 2048)
    u16* Wo_bf = (u16*)(ws + 165 * MB);
    // S7: Wx_bf (128 x 2048)
    u16* Wx_bf = (u16*)(ws + 169 * MB);
    // S8: Wdt_bf (2048 x 64)
    u16* Wdt_bf = (u16*)(ws + 169 * MB + 512 * 1024);
    const size_t NEED = 170 * MB;
    if (ws_size < NEED) return;  // diagnostic: clean numeric failure instead of page fault

    // conversions
    cvt_f32_bf16<<<8192, 256, 0, stream>>>(u, u_bf, 8388608);
    cvt_f32_bf16<<<4096, 256, 0, stream>>>(Wi, Wi_bf, 4194304);
    cvt_f32_bf16<<<2048, 256, 0, stream>>>(Wo, Wo_bf, 2097152);
    cvt_f32_bf16<<<128, 256, 0, stream>>>(Wdt, Wdt_bf, 131072);
    cvt_pad_xproj<<<1024, 256, 0, stream>>>(Wx, Wx_bf);

    // in_proj: xz(8192,4096) = u(8192,1024) @ Wi(4096,1024)^T  -> bf16
    gemm_nt<0><<<dim3(64, 32), 256, 0, stream>>>(u_bf, Wi_bf, 8192, 4096, 1024,
                                                 nullptr, xz, nullptr, nullptr);
    // conv + silu -> xc bf16 (token-major), x_t bf16 (channel-major)
    conv_silu<<<dim3(64, 32, 2), 256, 0, stream>>>(xz, conv_w, conv_b, xc, x_t);

    // x_proj: x_dbl(8192,128) = xc @ Wx_pad^T ; dtin = bf16(cols 0..63)
    gemm_nt<1><<<dim3(64, 1), 256, 0, stream>>>(xc, Wx_bf, 8192, 128, 2048,
                                                x_dbl, dtin, nullptr, nullptr);
    // dt_proj: dt_t[(b*2048+d)*4096+t] = bf16(softplus(dtin @ Wdt^T + dt_bias))
    gemm_nt<2><<<dim3(64, 16), 256, 0, stream>>>(dtin, Wdt_bf, 8192, 2048, 64,
                                                 nullptr, dt_t, dt_bias, nullptr);
    // scan + fused elementwise epilogue -> yy bf16
    scan_fused<<<256, 256, 0, stream>>>(dt_t, x_t, x_dbl, A_log, xz, D_in_, yybuf);

    // out_proj: out = yy @ Wo^T + D_skip*u
    gemm_nt<3><<<dim3(64, 8), 256, 0, stream>>>(yybuf, Wo_bf, 8192, 1024, 2048,
                                                out, nullptr, D_skip, u);
}

// Round 3
// 554.644 us; speedup vs baseline: 4.4232x; 4.4232x over previous
//
#include <hip/hip_runtime.h>

typedef unsigned short u16;
typedef unsigned int u32;
typedef __attribute__((ext_vector_type(8))) short s16x8;
typedef __attribute__((ext_vector_type(4))) float f32x4;

__device__ inline u16 f2bf(float f){
    u32 u = __float_as_uint(f);
    u32 r = (u + 0x7fffu + ((u >> 16) & 1u)) >> 16;
    return (u16)r;
}
__device__ inline float bf2f(u16 h){
    return __uint_as_float(((u32)h) << 16);
}

#define GLOAD_LDS16(g, l) __builtin_amdgcn_global_load_lds( \
    (__attribute__((address_space(1))) void*)(void*)(g),    \
    (__attribute__((address_space(3))) void*)(l), 16, 0, 0)

// ---------------------------------------------------------------------------
// Generic NT GEMM: C(M,N) = A(M,K) * B(N,K)^T, bf16 A, bf16 (or f32 if BF32) B.
// 128x128 tile, BK=64, 4 waves (2x2), each wave 64x64 via 4x4 mfma 16x16x32.
// EPI: 0 = split bf16 store: col<2048 -> Cb[row*2048+col], else Cb2[row*2048+col-2048]
//      1 = col<64 -> bf16 Cb[row*64+col]; 64<=col<96 -> f32 Cf[row*32+col-64]
//      2 = bf16 Cb[row*N+col] = softplus(acc + aux0[col])
//      3 = f32 Cf[row*N+col] = acc + aux0[col]*aux1[row*N+col]
// ---------------------------------------------------------------------------
template<int EPI, int BF32>
__global__ __launch_bounds__(256) void gemm_nt(
    const u16* __restrict__ A, const void* __restrict__ Bp,
    int M, int N, int K,
    float* __restrict__ Cf, u16* __restrict__ Cb, u16* __restrict__ Cb2,
    const float* __restrict__ aux0, const float* __restrict__ aux1)
{
    constexpr int BK = 64;
    __shared__ u16 As[128 * BK];
    __shared__ u16 Bs[128 * BK];
    const int tid  = threadIdx.x;
    const int lane = tid & 63, wave = tid >> 6;
    const int wr = wave >> 1, wc = wave & 1;
    const int bm = blockIdx.x, bn = blockIdx.y;
    const int l16 = lane & 15, lg = lane >> 4;

    const u16* Ab = A + (size_t)bm * 128 * K;
    const u16* Bb16 = BF32 ? nullptr : ((const u16*)Bp + (size_t)bn * 128 * K);
    const float* Bbf = BF32 ? ((const float*)Bp + (size_t)bn * 128 * K) : nullptr;

    f32x4 acc[4][4] = {};

    for (int kt = 0; kt < K; kt += BK) {
        #pragma unroll
        for (int p = 0; p < 4; p++) {
            int flat = (p * 256 + tid) * 8;
            int r = flat >> 6, c = flat & 63;
            GLOAD_LDS16(Ab + (size_t)r * K + kt + c, As + flat);
        }
        if (!BF32) {
            #pragma unroll
            for (int p = 0; p < 4; p++) {
                int flat = (p * 256 + tid) * 8;
                int r = flat >> 6, c = flat & 63;
                GLOAD_LDS16(Bb16 + (size_t)r * K + kt + c, Bs + flat);
            }
        } else {
            #pragma unroll
            for (int p = 0; p < 4; p++) {
                int flat = (p * 256 + tid) * 8;
                int r = flat >> 6, c = flat & 63;
                const float* src = Bbf + (size_t)r * K + kt + c;
                f32x4 v0 = *(const f32x4*)src;
                f32x4 v1 = *(const f32x4*)(src + 4);
                s16x8 bs;
                #pragma unroll
                for (int j = 0; j < 4; j++) {
                    bs[j]     = (short)f2bf(v0[j]);
                    bs[j + 4] = (short)f2bf(v1[j]);
                }
                *(s16x8*)&Bs[flat] = bs;
            }
        }
        asm volatile("s_waitcnt vmcnt(0)" ::: "memory");
        __syncthreads();
        #pragma unroll
        for (int kk = 0; kk < 2; kk++) {
            s16x8 a[4], b[4];
            #pragma unroll
            for (int m = 0; m < 4; m++)
                a[m] = *(const s16x8*)&As[(wr * 64 + m * 16 + l16) * BK + kk * 32 + lg * 8];
            #pragma unroll
            for (int n = 0; n < 4; n++)
                b[n] = *(const s16x8*)&Bs[(wc * 64 + n * 16 + l16) * BK + kk * 32 + lg * 8];
            #pragma unroll
            for (int m = 0; m < 4; m++)
                #pragma unroll
                for (int n = 0; n < 4; n++)
                    acc[m][n] = __builtin_amdgcn_mfma_f32_16x16x32_bf16(a[m], b[n], acc[m][n], 0, 0, 0);
        }
        __syncthreads();
    }

    const int row0 = bm * 128 + wr * 64 + lg * 4;
    const int col0 = bn * 128 + wc * 64 + l16;
    #pragma unroll
    for (int m = 0; m < 4; m++) {
        #pragma unroll
        for (int n = 0; n < 4; n++) {
            const int col = col0 + n * 16;
            #pragma unroll
            for (int r = 0; r < 4; r++) {
                const int row = row0 + m * 16 + r;
                float v = acc[m][n][r];
                if (EPI == 0) {
                    if (col < 2048) Cb[(size_t)row * 2048 + col] = f2bf(v);
                    else            Cb2[(size_t)row * 2048 + (col - 2048)] = f2bf(v);
                } else if (EPI == 1) {
                    if (col < 64)       Cb[(size_t)row * 64 + col] = f2bf(v);
                    else if (col < 96)  Cf[(size_t)row * 32 + (col - 64)] = v;
                } else if (EPI == 2) {
                    float t2 = v + aux0[col];
                    float sp = (t2 > 20.f) ? t2 : log1pf(__expf(t2));
                    Cb[(size_t)row * N + col] = f2bf(sp);
                } else {
                    float o = v + aux0[col] * aux1[(size_t)row * N + col];
                    Cf[(size_t)row * N + col] = o;
                }
            }
        }
    }
}

// ---------------------------------------------------------------------------
__global__ void cvt_f32_bf16(const float* __restrict__ in, u16* __restrict__ out, int n)
{
    int i = (blockIdx.x * 256 + threadIdx.x) * 4;
    if (i < n) {
        f32x4 v = *(const f32x4*)(in + i);
        ushort4 o;
        o.x = f2bf(v[0]); o.y = f2bf(v[1]); o.z = f2bf(v[2]); o.w = f2bf(v[3]);
        *(ushort4*)(out + i) = o;
    }
}

// x_proj_w (96,2048) -> bf16 padded to (128,2048), rows 96..127 = 0
__global__ void cvt_pad_xproj(const float* __restrict__ in, u16* __restrict__ out)
{
    int i = blockIdx.x * 256 + threadIdx.x;  // 0..262143
    int row = i >> 11, col = i & 2047;
    float v = (row < 96) ? in[row * 2048 + col] : 0.f;
    out[i] = f2bf(v);
}

// ---------------------------------------------------------------------------
// Depthwise causal conv (D_CONV=4) + bias + SiLU. Sliding window, no LDS.
// xzx token-major (8192,2048) bf16 -> xc token-major (8192,2048) bf16.
// grid (64, 32, 2), block 256: 64 d-lanes x 4 t-groups, 16 consecutive t each.
// ---------------------------------------------------------------------------
__global__ __launch_bounds__(256) void conv_silu(
    const u16* __restrict__ xzx, const float* __restrict__ cw,
    const float* __restrict__ cb, u16* __restrict__ xc)
{
    const int tid = threadIdx.x;
    const int dl = tid & 63, tg = tid >> 6;
    const int d = blockIdx.y * 64 + dl;
    const int t0 = blockIdx.x * 64 + tg * 16;
    const int b = blockIdx.z;
    const float c0 = cw[d * 4 + 0], c1 = cw[d * 4 + 1];
    const float c2 = cw[d * 4 + 2], c3 = cw[d * 4 + 3];
    const float bias = cb[d];
    const u16* xp = xzx + (size_t)(b * 4096) * 2048 + d;
    u16* op = xc + (size_t)(b * 4096) * 2048 + d;
    float w0 = (t0 >= 3) ? bf2f(xp[(size_t)(t0 - 3) * 2048]) : 0.f;
    float w1 = (t0 >= 2) ? bf2f(xp[(size_t)(t0 - 2) * 2048]) : 0.f;
    float w2 = (t0 >= 1) ? bf2f(xp[(size_t)(t0 - 1) * 2048]) : 0.f;
    #pragma unroll
    for (int k = 0; k < 16; k++) {
        int t = t0 + k;
        float cur = bf2f(xp[(size_t)t * 2048]);
        float s = bias + w0 * c0 + w1 * c1 + w2 * c2 + cur * c3;
        float v = s * __fdividef(1.f, 1.f + __expf(-s));
        op[(size_t)t * 2048] = f2bf(v);
        w0 = w1; w1 = w2; w2 = cur;
    }
}

// ---------------------------------------------------------------------------
// Scan phase 1: per-chunk local scan (h0=0) -> Aagg, Bagg (bf16).
// Each thread owns all 16 states of one (b,d) channel for one 64-step chunk.
// grid (8, 64, 2), block 256 (d = bx*256+tid, c = by, b = bz).
// Aagg/Bagg layout: [b][d][n][c] (c contiguous).
// ---------------------------------------------------------------------------
__global__ __launch_bounds__(256) void scan_p1(
    const u16* __restrict__ dtb, const u16* __restrict__ xc,
    const float* __restrict__ xBC, const float* __restrict__ A_log,
    u16* __restrict__ Aagg, u16* __restrict__ Bagg)
{
    __shared__ float Bsh[64][16];
    const int tid = threadIdx.x;
    const int d = blockIdx.x * 256 + tid;
    const int c = blockIdx.y, b = blockIdx.z;

    {   // stage B (16 floats per token, 64 tokens)
        int ti = tid >> 2, p = tid & 3;
        f32x4 bv = *(const f32x4*)(xBC + ((size_t)(b * 4096 + c * 64 + ti)) * 32 + p * 4);
        *(f32x4*)&Bsh[ti][p * 4] = bv;
    }
    __syncthreads();

    float Adn[16];
    #pragma unroll
    for (int q = 0; q < 4; q++) {
        f32x4 al = *(const f32x4*)(A_log + (size_t)d * 16 + q * 4);
        #pragma unroll
        for (int j = 0; j < 4; j++) Adn[q * 4 + j] = -__expf(al[j]);
    }

    const size_t base = (size_t)(b * 4096 + c * 64) * 2048 + d;
    const u16* dtp = dtb + base;
    const u16* xp  = xc  + base;

    float h[16];
    #pragma unroll
    for (int n = 0; n < 16; n++) h[n] = 0.f;
    float sumdt = 0.f;

    float dtv = bf2f(dtp[0]), xv = bf2f(xp[0]);
    for (int t = 0; t < 64; t++) {
        float ndt = 0.f, nx = 0.f;
        if (t < 63) { ndt = bf2f(dtp[(size_t)(t + 1) * 2048]); nx = bf2f(xp[(size_t)(t + 1) * 2048]); }
        float dtx = dtv * xv;
        sumdt += dtv;
        f32x4 B0 = *(const f32x4*)&Bsh[t][0];
        f32x4 B1 = *(const f32x4*)&Bsh[t][4];
        f32x4 B2 = *(const f32x4*)&Bsh[t][8];
        f32x4 B3 = *(const f32x4*)&Bsh[t][12];
        #pragma unroll
        for (int n = 0; n < 16; n++) {
            float Bv = (n < 4) ? B0[n] : (n < 8) ? B1[n - 4] : (n < 12) ? B2[n - 8] : B3[n - 12];
            float a = __expf(Adn[n] * dtv);
            h[n] = fmaf(a, h[n], dtx * Bv);
        }
        dtv = ndt; xv = nx;
    }

    const size_t abase = ((size_t)(b * 2048 + d) * 16) * 64 + c;
    #pragma unroll
    for (int n = 0; n < 16; n++) {
        Aagg[abase + (size_t)n * 64] = f2bf(__expf(Adn[n] * sumdt));
        Bagg[abase + (size_t)n * 64] = f2bf(h[n]);
    }
}

// ---------------------------------------------------------------------------
// Scan phase 2: sequential combine over 64 chunks per (b,d,n).
// In-place: Bagg becomes H0 (state entering chunk c). All in registers.
// grid 256 x 256 (65536 threads).
// ---------------------------------------------------------------------------
__global__ __launch_bounds__(256) void scan_p2(
    const u16* __restrict__ Aagg, u16* __restrict__ BaggH0)
{
    const int gid = blockIdx.x * 256 + threadIdx.x;  // = (b*2048+d)*16+n
    const size_t base = (size_t)gid * 64;
    s16x8 Ar[8], Br[8];
    #pragma unroll
    for (int i = 0; i < 8; i++) {
        Ar[i] = *(const s16x8*)(Aagg + base + i * 8);
        Br[i] = *(const s16x8*)(BaggH0 + base + i * 8);
    }
    s16x8 Hr[8];
    float h = 0.f;
    #pragma unroll
    for (int i = 0; i < 8; i++) {
        #pragma unroll
        for (int j = 0; j < 8; j++) {
            float ac = bf2f((u16)Ar[i][j]);
            float bc = bf2f((u16)Br[i][j]);
            Hr[i][j] = (short)f2bf(h);
            h = fmaf(ac, h, bc);
        }
    }
    #pragma unroll
    for (int i = 0; i < 8; i++)
        *(s16x8*)(BaggH0 + base + i * 8) = Hr[i];
}

// ---------------------------------------------------------------------------
// Scan phase 3: rerun chunk scan from H0, compute y, fused epilogue
// (y + x*D_in) * silu(z) -> yy bf16 token-major.
// grid (8, 64, 2), block 256.
// ---------------------------------------------------------------------------
__global__ __launch_bounds__(256) void scan_p3(
    const u16* __restrict__ dtb, const u16* __restrict__ xc,
    const float* __restrict__ xBC, const float* __restrict__ A_log,
    const u16* __restrict__ H0, const u16* __restrict__ xzz,
    const float* __restrict__ D_in, u16* __restrict__ yy)
{
    __shared__ float BCs[64][32];
    const int tid = threadIdx.x;
    const int d = blockIdx.x * 256 + tid;
    const int c = blockIdx.y, b = blockIdx.z;

    {   // stage B+C (32 floats per token, 64 tokens)
        int ti = tid >> 2, p = tid & 3;
        const float* src = xBC + ((size_t)(b * 4096 + c * 64 + ti)) * 32 + p * 8;
        f32x4 v0 = *(const f32x4*)src;
        f32x4 v1 = *(const f32x4*)(src + 4);
        *(f32x4*)&BCs[ti][p * 8] = v0;
        *(f32x4*)&BCs[ti][p * 8 + 4] = v1;
    }
    __syncthreads();

    float Adn[16];
    #pragma unroll
    for (int q = 0; q < 4; q++) {
        f32x4 al = *(const f32x4*)(A_log + (size_t)d * 16 + q * 4);
        #pragma unroll
        for (int j = 0; j < 4; j++) Adn[q * 4 + j] = -__expf(al[j]);
    }
    const float Dd = D_in[d];

    float h[16];
    const size_t hbase = ((size_t)(b * 2048 + d) * 16) * 64 + c;
    #pragma unroll
    for (int n = 0; n < 16; n++) h[n] = bf2f(H0[hbase + (size_t)n * 64]);

    const size_t base = (size_t)(b * 4096 + c * 64) * 2048 + d;
    const u16* dtp = dtb + base;
    const u16* xp  = xc  + base;
    const u16* zp  = xzz + base;
    u16* yp = yy + base;

    float dtv = bf2f(dtp[0]), xv = bf2f(xp[0]), zv = bf2f(zp[0]);
    for (int t = 0; t < 64; t++) {
        float ndt = 0.f, nx = 0.f, nz = 0.f;
        if (t < 63) {
            ndt = bf2f(dtp[(size_t)(t + 1) * 2048]);
            nx  = bf2f(xp[(size_t)(t + 1) * 2048]);
            nz  = bf2f(zp[(size_t)(t + 1) * 2048]);
        }
        float dtx = dtv * xv;
        f32x4 B0 = *(const f32x4*)&BCs[t][0];
        f32x4 B1 = *(const f32x4*)&BCs[t][4];
        f32x4 B2 = *(const f32x4*)&BCs[t][8];
        f32x4 B3 = *(const f32x4*)&BCs[t][12];
        f32x4 C0 = *(const f32x4*)&BCs[t][16];
        f32x4 C1 = *(const f32x4*)&BCs[t][20];
        f32x4 C2 = *(const f32x4*)&BCs[t][24];
        f32x4 C3 = *(const f32x4*)&BCs[t][28];
        float y = 0.f;
        #pragma unroll
        for (int n = 0; n < 16; n++) {
            float Bv = (n < 4) ? B0[n] : (n < 8) ? B1[n - 4] : (n < 12) ? B2[n - 8] : B3[n - 12];
            float Cv = (n < 4) ? C0[n] : (n < 8) ? C1[n - 4] : (n < 12) ? C2[n - 8] : C3[n - 12];
            float a = __expf(Adn[n] * dtv);
            h[n] = fmaf(a, h[n], dtx * Bv);
            y = fmaf(h[n], Cv, y);
        }
        float sz = zv * __fdividef(1.f, 1.f + __expf(-zv));
        float val = fmaf(xv, Dd, y) * sz;
        yp[(size_t)t * 2048] = f2bf(val);
        dtv = ndt; xv = nx; zv = nz;
    }
}

// ---------------------------------------------------------------------------
extern "C" void kernel_launch(void* const* d_in, const int* in_sizes, int n_in,
                              void* d_out, int out_size, void* d_ws, size_t ws_size,
                              hipStream_t stream)
{
    const float* u       = (const float*)d_in[0];   // (2,4096,1024)
    const float* Wi      = (const float*)d_in[1];   // (4096,1024)
    const float* conv_w  = (const float*)d_in[2];   // (2048,4)
    const float* conv_b  = (const float*)d_in[3];   // (2048)
    const float* Wx      = (const float*)d_in[4];   // (96,2048)
    const float* Wdt     = (const float*)d_in[5];   // (2048,64)
    const float* dt_bias = (const float*)d_in[6];   // (2048)
    const float* A_log   = (const float*)d_in[7];   // (2048,16)
    const float* D_in_   = (const float*)d_in[8];   // (2048)
    const float* Wo      = (const float*)d_in[9];   // (1024,2048)
    const float* D_skip  = (const float*)d_in[10];  // (1024)
    float* out = (float*)d_out;
    (void)in_sizes; (void)n_in; (void)out_size;

    // ---- workspace layout with live-range aliasing (169 MB) ----
    const size_t MB = 1u << 20;
    char* ws = (char*)d_ws;
    u16*   xzx    = (u16*)(ws + 0);            // [in_proj..conv]   32MB
    u16*   Aagg   = (u16*)(ws + 0);            // [p1..p2]           8MB (after xzx dead)
    u16*   dtin   = (u16*)(ws + 8 * MB);       // [x_proj..dt_proj]  1MB
    u16*   xzz    = (u16*)(ws + 32 * MB);      // [in_proj..p3]     32MB
    u16*   xc     = (u16*)(ws + 64 * MB);      // [conv..p3]        32MB
    u16*   u_bf   = (u16*)(ws + 96 * MB);      // [cvt..in_proj]    16MB
    u16*   Wi_bf  = (u16*)(ws + 112 * MB);     // [cvt..in_proj]     8MB
    u16*   dtb    = (u16*)(ws + 96 * MB);      // [dt_proj..p3]     32MB (after u_bf/Wi_bf dead)
    u16*   Wx_bf  = (u16*)(ws + 128 * MB);     // [cvt..x_proj]    0.5MB
    u16*   Wdt_bf = (u16*)(ws + 128 * MB + 512 * 1024); // [cvt..dt_proj] 0.25MB
    u16*   yybuf  = (u16*)(ws + 128 * MB);     // [p3..out_proj]    32MB (after Wx/Wdt dead)
    u16*   BaggH0 = (u16*)(ws + 160 * MB);     // [p1..p3]           8MB
    float* xBC    = (float*)(ws + 168 * MB);   // [x_proj..p3]       1MB
    const size_t NEED = 169 * MB;
    if (ws_size < NEED) return;

    // conversions
    cvt_f32_bf16<<<8192, 256, 0, stream>>>(u, u_bf, 8388608);
    cvt_f32_bf16<<<4096, 256, 0, stream>>>(Wi, Wi_bf, 4194304);
    cvt_f32_bf16<<<128, 256, 0, stream>>>(Wdt, Wdt_bf, 131072);
    cvt_pad_xproj<<<1024, 256, 0, stream>>>(Wx, Wx_bf);

    // in_proj: u(8192,1024) @ Wi^T -> xzx (cols 0..2047), xzz (cols 2048..4095)
    gemm_nt<0, 0><<<dim3(64, 32), 256, 0, stream>>>(u_bf, Wi_bf, 8192, 4096, 1024,
                                                    nullptr, xzx, xzz, nullptr, nullptr);
    // conv + silu -> xc (token-major bf16)
    conv_silu<<<dim3(64, 32, 2), 256, 0, stream>>>(xzx, conv_w, conv_b, xc);

    // x_proj: xc @ Wx_pad^T -> dtin (cols<64, bf16), xBC (cols 64..95, f32)
    gemm_nt<1, 0><<<dim3(64, 1), 256, 0, stream>>>(xc, Wx_bf, 8192, 128, 2048,
                                                   xBC, dtin, nullptr, nullptr, nullptr);
    // dt_proj: dtb[tok,d] = bf16(softplus(dtin @ Wdt^T + dt_bias))  (token-major)
    gemm_nt<2, 0><<<dim3(64, 16), 256, 0, stream>>>(dtin, Wdt_bf, 8192, 2048, 64,
                                                    nullptr, dtb, nullptr, dt_bias, nullptr);

    // chunk-parallel scan
    scan_p1<<<dim3(8, 64, 2), 256, 0, stream>>>(dtb, xc, xBC, A_log, Aagg, BaggH0);
    scan_p2<<<256, 256, 0, stream>>>(Aagg, BaggH0);
    scan_p3<<<dim3(8, 64, 2), 256, 0, stream>>>(dtb, xc, xBC, A_log, BaggH0, xzz,
                                                D_in_, yybuf);

    // out_proj: out = yy @ Wo^T + D_skip*u   (Wo staged f32->bf16 in-kernel)
    gemm_nt<3, 1><<<dim3(64, 8), 256, 0, stream>>>(yybuf, Wo, 8192, 1024, 2048,
                                                   out, nullptr, nullptr, D_skip, u);
}

// Round 4
// 409.073 us; speedup vs baseline: 5.9972x; 1.3559x over previous
//
#include <hip/hip_runtime.h>

typedef unsigned short u16;
typedef unsigned int u32;
typedef __attribute__((ext_vector_type(8))) short s16x8;
typedef __attribute__((ext_vector_type(4))) float f32x4;

__device__ inline u16 f2bf(float f){
    u32 u = __float_as_uint(f);
    u32 r = (u + 0x7fffu + ((u >> 16) & 1u)) >> 16;
    return (u16)r;
}
__device__ inline float bf2f(u16 h){
    return __uint_as_float(((u32)h) << 16);
}

#define GLOAD_LDS16(g, l) __builtin_amdgcn_global_load_lds( \
    (__attribute__((address_space(1))) void*)(void*)(g),    \
    (__attribute__((address_space(3))) void*)(l), 16, 0, 0)

// ---------------------------------------------------------------------------
// Generic NT GEMM: C(M,N) = A(M,K) * B(N,K)^T, bf16 inputs, fp32 accum.
// 128x128 tile, BK=64, 4 waves (2x2), each wave 64x64 via 4x4 mfma 16x16x32.
// EPI: 0 = split bf16 store: col<2048 -> Cb[row*2048+col], else Cb2[...]
//      2 = bf16 Cb[row*N+col] = softplus(acc + aux0[col])   (fast softplus)
//      3 = f32 Cf[row*N+col] = acc + aux0[col]*aux1[row*N+col]
// ---------------------------------------------------------------------------
template<int EPI>
__global__ __launch_bounds__(256) void gemm_nt(
    const u16* __restrict__ A, const u16* __restrict__ B,
    int M, int N, int K,
    float* __restrict__ Cf, u16* __restrict__ Cb, u16* __restrict__ Cb2,
    const float* __restrict__ aux0, const float* __restrict__ aux1)
{
    constexpr int BK = 64;
    __shared__ u16 As[128 * BK];
    __shared__ u16 Bs[128 * BK];
    const int tid  = threadIdx.x;
    const int lane = tid & 63, wave = tid >> 6;
    const int wr = wave >> 1, wc = wave & 1;
    const int bm = blockIdx.x, bn = blockIdx.y;
    const int l16 = lane & 15, lg = lane >> 4;

    const u16* Ab = A + (size_t)bm * 128 * K;
    const u16* Bb = B + (size_t)bn * 128 * K;

    f32x4 acc[4][4] = {};

    for (int kt = 0; kt < K; kt += BK) {
        #pragma unroll
        for (int p = 0; p < 4; p++) {
            int flat = (p * 256 + tid) * 8;
            int r = flat >> 6, c = flat & 63;
            GLOAD_LDS16(Ab + (size_t)r * K + kt + c, As + flat);
        }
        #pragma unroll
        for (int p = 0; p < 4; p++) {
            int flat = (p * 256 + tid) * 8;
            int r = flat >> 6, c = flat & 63;
            GLOAD_LDS16(Bb + (size_t)r * K + kt + c, Bs + flat);
        }
        asm volatile("s_waitcnt vmcnt(0)" ::: "memory");
        __syncthreads();
        #pragma unroll
        for (int kk = 0; kk < 2; kk++) {
            s16x8 a[4], b[4];
            #pragma unroll
            for (int m = 0; m < 4; m++)
                a[m] = *(const s16x8*)&As[(wr * 64 + m * 16 + l16) * BK + kk * 32 + lg * 8];
            #pragma unroll
            for (int n = 0; n < 4; n++)
                b[n] = *(const s16x8*)&Bs[(wc * 64 + n * 16 + l16) * BK + kk * 32 + lg * 8];
            #pragma unroll
            for (int m = 0; m < 4; m++)
                #pragma unroll
                for (int n = 0; n < 4; n++)
                    acc[m][n] = __builtin_amdgcn_mfma_f32_16x16x32_bf16(a[m], b[n], acc[m][n], 0, 0, 0);
        }
        __syncthreads();
    }

    const int row0 = bm * 128 + wr * 64 + lg * 4;
    const int col0 = bn * 128 + wc * 64 + l16;
    #pragma unroll
    for (int m = 0; m < 4; m++) {
        #pragma unroll
        for (int n = 0; n < 4; n++) {
            const int col = col0 + n * 16;
            #pragma unroll
            for (int r = 0; r < 4; r++) {
                const int row = row0 + m * 16 + r;
                float v = acc[m][n][r];
                if (EPI == 0) {
                    if (col < 2048) Cb[(size_t)row * 2048 + col] = f2bf(v);
                    else            Cb2[(size_t)row * 2048 + (col - 2048)] = f2bf(v);
                } else if (EPI == 2) {
                    float t2 = v + aux0[col];
                    float sp = (t2 > 15.f) ? t2 : __logf(1.f + __expf(t2));
                    Cb[(size_t)row * N + col] = f2bf(sp);
                } else {
                    float o = v + aux0[col] * aux1[(size_t)row * N + col];
                    Cf[(size_t)row * N + col] = o;
                }
            }
        }
    }
}

// ---------------------------------------------------------------------------
// x_proj split-K: partials[sk][8192][128] = xc[.,kchunk] @ Wx_bf[.,kchunk]^T
// grid (64, SK=8), block 256. K-chunk = 256 (4 BK iters).
// ---------------------------------------------------------------------------
__global__ __launch_bounds__(256) void gemm_xproj_sk(
    const u16* __restrict__ A, const u16* __restrict__ B,
    float* __restrict__ part)
{
    constexpr int BK = 64, K = 2048;
    __shared__ u16 As[128 * BK];
    __shared__ u16 Bs[128 * BK];
    const int tid  = threadIdx.x;
    const int lane = tid & 63, wave = tid >> 6;
    const int wr = wave >> 1, wc = wave & 1;
    const int bm = blockIdx.x, sk = blockIdx.y;
    const int l16 = lane & 15, lg = lane >> 4;

    const u16* Ab = A + (size_t)bm * 128 * K;
    const u16* Bb = B;
    const int kt0 = sk * 256;

    f32x4 acc[4][4] = {};

    for (int kt = kt0; kt < kt0 + 256; kt += BK) {
        #pragma unroll
        for (int p = 0; p < 4; p++) {
            int flat = (p * 256 + tid) * 8;
            int r = flat >> 6, c = flat & 63;
            GLOAD_LDS16(Ab + (size_t)r * K + kt + c, As + flat);
        }
        #pragma unroll
        for (int p = 0; p < 4; p++) {
            int flat = (p * 256 + tid) * 8;
            int r = flat >> 6, c = flat & 63;
            GLOAD_LDS16(Bb + (size_t)r * K + kt + c, Bs + flat);
        }
        asm volatile("s_waitcnt vmcnt(0)" ::: "memory");
        __syncthreads();
        #pragma unroll
        for (int kk = 0; kk < 2; kk++) {
            s16x8 a[4], b[4];
            #pragma unroll
            for (int m = 0; m < 4; m++)
                a[m] = *(const s16x8*)&As[(wr * 64 + m * 16 + l16) * BK + kk * 32 + lg * 8];
            #pragma unroll
            for (int n = 0; n < 4; n++)
                b[n] = *(const s16x8*)&Bs[(wc * 64 + n * 16 + l16) * BK + kk * 32 + lg * 8];
            #pragma unroll
            for (int m = 0; m < 4; m++)
                #pragma unroll
                for (int n = 0; n < 4; n++)
                    acc[m][n] = __builtin_amdgcn_mfma_f32_16x16x32_bf16(a[m], b[n], acc[m][n], 0, 0, 0);
        }
        __syncthreads();
    }

    float* pb = part + (size_t)sk * 8192 * 128;
    const int row0 = bm * 128 + wr * 64 + lg * 4;
    const int col0 = wc * 64 + l16;
    #pragma unroll
    for (int m = 0; m < 4; m++)
        #pragma unroll
        for (int n = 0; n < 4; n++)
            #pragma unroll
            for (int r = 0; r < 4; r++)
                pb[(size_t)(row0 + m * 16 + r) * 128 + col0 + n * 16] = acc[m][n][r];
}

// Combine SK=8 partials; cols<64 -> dtin bf16, 64..95 -> xBC f32.
__global__ __launch_bounds__(256) void combine_xproj(
    const float* __restrict__ part, u16* __restrict__ dtin,
    float* __restrict__ xBC)
{
    const int gid = blockIdx.x * 256 + threadIdx.x;  // 0 .. 8192*128-1
    const int row = gid >> 7, col = gid & 127;
    float s = 0.f;
    #pragma unroll
    for (int sk = 0; sk < 8; sk++) s += part[(size_t)sk * 8192 * 128 + gid];
    if (col < 64)      dtin[(size_t)row * 64 + col] = f2bf(s);
    else if (col < 96) xBC[(size_t)row * 32 + (col - 64)] = s;
}

// ---------------------------------------------------------------------------
__global__ void cvt_f32_bf16(const float* __restrict__ in, u16* __restrict__ out, int n)
{
    int i = (blockIdx.x * 256 + threadIdx.x) * 4;
    if (i < n) {
        f32x4 v = *(const f32x4*)(in + i);
        ushort4 o;
        o.x = f2bf(v[0]); o.y = f2bf(v[1]); o.z = f2bf(v[2]); o.w = f2bf(v[3]);
        *(ushort4*)(out + i) = o;
    }
}

// x_proj_w (96,2048) -> bf16 padded to (128,2048), rows 96..127 = 0
__global__ void cvt_pad_xproj(const float* __restrict__ in, u16* __restrict__ out)
{
    int i = blockIdx.x * 256 + threadIdx.x;  // 0..262143
    int row = i >> 11, col = i & 2047;
    float v = (row < 96) ? in[row * 2048 + col] : 0.f;
    out[i] = f2bf(v);
}

// ---------------------------------------------------------------------------
// Depthwise causal conv (D_CONV=4) + bias + SiLU. Sliding window, no LDS.
// ---------------------------------------------------------------------------
__global__ __launch_bounds__(256) void conv_silu(
    const u16* __restrict__ xzx, const float* __restrict__ cw,
    const float* __restrict__ cb, u16* __restrict__ xc)
{
    const int tid = threadIdx.x;
    const int dl = tid & 63, tg = tid >> 6;
    const int d = blockIdx.y * 64 + dl;
    const int t0 = blockIdx.x * 64 + tg * 16;
    const int b = blockIdx.z;
    const float c0 = cw[d * 4 + 0], c1 = cw[d * 4 + 1];
    const float c2 = cw[d * 4 + 2], c3 = cw[d * 4 + 3];
    const float bias = cb[d];
    const u16* xp = xzx + (size_t)(b * 4096) * 2048 + d;
    u16* op = xc + (size_t)(b * 4096) * 2048 + d;
    float w0 = (t0 >= 3) ? bf2f(xp[(size_t)(t0 - 3) * 2048]) : 0.f;
    float w1 = (t0 >= 2) ? bf2f(xp[(size_t)(t0 - 2) * 2048]) : 0.f;
    float w2 = (t0 >= 1) ? bf2f(xp[(size_t)(t0 - 1) * 2048]) : 0.f;
    #pragma unroll
    for (int k = 0; k < 16; k++) {
        int t = t0 + k;
        float cur = bf2f(xp[(size_t)t * 2048]);
        float s = bias + w0 * c0 + w1 * c1 + w2 * c2 + cur * c3;
        float v = s * __fdividef(1.f, 1.f + __expf(-s));
        op[(size_t)t * 2048] = f2bf(v);
        w0 = w1; w1 = w2; w2 = cur;
    }
}

// ---------------------------------------------------------------------------
// Scan phase 1: per-chunk local scan (h0=0) -> Aagg, Bagg (bf16).
// grid (8, 64, 2), block 256. Aagg/Bagg layout: [b][d][n][c].
// ---------------------------------------------------------------------------
__global__ __launch_bounds__(256) void scan_p1(
    const u16* __restrict__ dtb, const u16* __restrict__ xc,
    const float* __restrict__ xBC, const float* __restrict__ A_log,
    u16* __restrict__ Aagg, u16* __restrict__ Bagg)
{
    __shared__ float Bsh[64][16];
    const int tid = threadIdx.x;
    const int d = blockIdx.x * 256 + tid;
    const int c = blockIdx.y, b = blockIdx.z;

    {
        int ti = tid >> 2, p = tid & 3;
        f32x4 bv = *(const f32x4*)(xBC + ((size_t)(b * 4096 + c * 64 + ti)) * 32 + p * 4);
        *(f32x4*)&Bsh[ti][p * 4] = bv;
    }
    __syncthreads();

    float Adn[16];
    #pragma unroll
    for (int q = 0; q < 4; q++) {
        f32x4 al = *(const f32x4*)(A_log + (size_t)d * 16 + q * 4);
        #pragma unroll
        for (int j = 0; j < 4; j++) Adn[q * 4 + j] = -__expf(al[j]);
    }

    const size_t base = (size_t)(b * 4096 + c * 64) * 2048 + d;
    const u16* dtp = dtb + base;
    const u16* xp  = xc  + base;

    float h[16];
    #pragma unroll
    for (int n = 0; n < 16; n++) h[n] = 0.f;
    float sumdt = 0.f;

    float dtv = bf2f(dtp[0]), xv = bf2f(xp[0]);
    for (int t = 0; t < 64; t++) {
        float ndt = 0.f, nx = 0.f;
        if (t < 63) { ndt = bf2f(dtp[(size_t)(t + 1) * 2048]); nx = bf2f(xp[(size_t)(t + 1) * 2048]); }
        float dtx = dtv * xv;
        sumdt += dtv;
        f32x4 B0 = *(const f32x4*)&Bsh[t][0];
        f32x4 B1 = *(const f32x4*)&Bsh[t][4];
        f32x4 B2 = *(const f32x4*)&Bsh[t][8];
        f32x4 B3 = *(const f32x4*)&Bsh[t][12];
        #pragma unroll
        for (int n = 0; n < 16; n++) {
            float Bv = (n < 4) ? B0[n] : (n < 8) ? B1[n - 4] : (n < 12) ? B2[n - 8] : B3[n - 12];
            float a = __expf(Adn[n] * dtv);
            h[n] = fmaf(a, h[n], dtx * Bv);
        }
        dtv = ndt; xv = nx;
    }

    const size_t abase = ((size_t)(b * 2048 + d) * 16) * 64 + c;
    #pragma unroll
    for (int n = 0; n < 16; n++) {
        Aagg[abase + (size_t)n * 64] = f2bf(__expf(Adn[n] * sumdt));
        Bagg[abase + (size_t)n * 64] = f2bf(h[n]);
    }
}

// ---------------------------------------------------------------------------
// Scan phase 2: sequential combine over 64 chunks per (b,d,n). In-place.
// ---------------------------------------------------------------------------
__global__ __launch_bounds__(256) void scan_p2(
    const u16* __restrict__ Aagg, u16* __restrict__ BaggH0)
{
    const int gid = blockIdx.x * 256 + threadIdx.x;
    const size_t base = (size_t)gid * 64;
    s16x8 Ar[8], Br[8];
    #pragma unroll
    for (int i = 0; i < 8; i++) {
        Ar[i] = *(const s16x8*)(Aagg + base + i * 8);
        Br[i] = *(const s16x8*)(BaggH0 + base + i * 8);
    }
    s16x8 Hr[8];
    float h = 0.f;
    #pragma unroll
    for (int i = 0; i < 8; i++) {
        #pragma unroll
        for (int j = 0; j < 8; j++) {
            float ac = bf2f((u16)Ar[i][j]);
            float bc = bf2f((u16)Br[i][j]);
            Hr[i][j] = (short)f2bf(h);
            h = fmaf(ac, h, bc);
        }
    }
    #pragma unroll
    for (int i = 0; i < 8; i++)
        *(s16x8*)(BaggH0 + base + i * 8) = Hr[i];
}

// ---------------------------------------------------------------------------
// Scan phase 3: rerun chunk scan from H0, fused epilogue -> yy bf16.
// ---------------------------------------------------------------------------
__global__ __launch_bounds__(256) void scan_p3(
    const u16* __restrict__ dtb, const u16* __restrict__ xc,
    const float* __restrict__ xBC, const float* __restrict__ A_log,
    const u16* __restrict__ H0, const u16* __restrict__ xzz,
    const float* __restrict__ D_in, u16* __restrict__ yy)
{
    __shared__ float BCs[64][32];
    const int tid = threadIdx.x;
    const int d = blockIdx.x * 256 + tid;
    const int c = blockIdx.y, b = blockIdx.z;

    {
        int ti = tid >> 2, p = tid & 3;
        const float* src = xBC + ((size_t)(b * 4096 + c * 64 + ti)) * 32 + p * 8;
        f32x4 v0 = *(const f32x4*)src;
        f32x4 v1 = *(const f32x4*)(src + 4);
        *(f32x4*)&BCs[ti][p * 8] = v0;
        *(f32x4*)&BCs[ti][p * 8 + 4] = v1;
    }
    __syncthreads();

    float Adn[16];
    #pragma unroll
    for (int q = 0; q < 4; q++) {
        f32x4 al = *(const f32x4*)(A_log + (size_t)d * 16 + q * 4);
        #pragma unroll
        for (int j = 0; j < 4; j++) Adn[q * 4 + j] = -__expf(al[j]);
    }
    const float Dd = D_in[d];

    float h[16];
    const size_t hbase = ((size_t)(b * 2048 + d) * 16) * 64 + c;
    #pragma unroll
    for (int n = 0; n < 16; n++) h[n] = bf2f(H0[hbase + (size_t)n * 64]);

    const size_t base = (size_t)(b * 4096 + c * 64) * 2048 + d;
    const u16* dtp = dtb + base;
    const u16* xp  = xc  + base;
    const u16* zp  = xzz + base;
    u16* yp = yy + base;

    float dtv = bf2f(dtp[0]), xv = bf2f(xp[0]), zv = bf2f(zp[0]);
    for (int t = 0; t < 64; t++) {
        float ndt = 0.f, nx = 0.f, nz = 0.f;
        if (t < 63) {
            ndt = bf2f(dtp[(size_t)(t + 1) * 2048]);
            nx  = bf2f(xp[(size_t)(t + 1) * 2048]);
            nz  = bf2f(zp[(size_t)(t + 1) * 2048]);
        }
        float dtx = dtv * xv;
        f32x4 B0 = *(const f32x4*)&BCs[t][0];
        f32x4 B1 = *(const f32x4*)&BCs[t][4];
        f32x4 B2 = *(const f32x4*)&BCs[t][8];
        f32x4 B3 = *(const f32x4*)&BCs[t][12];
        f32x4 C0 = *(const f32x4*)&BCs[t][16];
        f32x4 C1 = *(const f32x4*)&BCs[t][20];
        f32x4 C2 = *(const f32x4*)&BCs[t][24];
        f32x4 C3 = *(const f32x4*)&BCs[t][28];
        float y = 0.f;
        #pragma unroll
        for (int n = 0; n < 16; n++) {
            float Bv = (n < 4) ? B0[n] : (n < 8) ? B1[n - 4] : (n < 12) ? B2[n - 8] : B3[n - 12];
            float Cv = (n < 4) ? C0[n] : (n < 8) ? C1[n - 4] : (n < 12) ? C2[n - 8] : C3[n - 12];
            float a = __expf(Adn[n] * dtv);
            h[n] = fmaf(a, h[n], dtx * Bv);
            y = fmaf(h[n], Cv, y);
        }
        float sz = zv * __fdividef(1.f, 1.f + __expf(-zv));
        float val = fmaf(xv, Dd, y) * sz;
        yp[(size_t)t * 2048] = f2bf(val);
        dtv = ndt; xv = nx; zv = nz;
    }
}

// ---------------------------------------------------------------------------
extern "C" void kernel_launch(void* const* d_in, const int* in_sizes, int n_in,
                              void* d_out, int out_size, void* d_ws, size_t ws_size,
                              hipStream_t stream)
{
    const float* u       = (const float*)d_in[0];
    const float* Wi      = (const float*)d_in[1];
    const float* conv_w  = (const float*)d_in[2];
    const float* conv_b  = (const float*)d_in[3];
    const float* Wx      = (const float*)d_in[4];
    const float* Wdt     = (const float*)d_in[5];
    const float* dt_bias = (const float*)d_in[6];
    const float* A_log   = (const float*)d_in[7];
    const float* D_in_   = (const float*)d_in[8];
    const float* Wo      = (const float*)d_in[9];
    const float* D_skip  = (const float*)d_in[10];
    float* out = (float*)d_out;
    (void)in_sizes; (void)n_in; (void)out_size;

    // ---- workspace layout with live-range aliasing (166 MB) ----
    const size_t MB = 1u << 20;
    char* ws = (char*)d_ws;
    u16*   xzx    = (u16*)(ws + 0);            // [in_proj..conv]      32MB
    float* xpart  = (float*)(ws + 0);          // [xproj_sk..combine]  32MB
    u16*   Aagg   = (u16*)(ws + 0);            // [p1..p2]              8MB
    u16*   BaggH0 = (u16*)(ws + 8 * MB);       // [p1..p3]              8MB
    u16*   xzz    = (u16*)(ws + 32 * MB);      // [in_proj..p3]        32MB
    u16*   xc     = (u16*)(ws + 64 * MB);      // [conv..p3]           32MB
    u16*   u_bf   = (u16*)(ws + 96 * MB);      // [cvt..in_proj]       16MB
    u16*   Wi_bf  = (u16*)(ws + 112 * MB);     // [cvt..in_proj]        8MB
    u16*   dtb    = (u16*)(ws + 96 * MB);      // [dt_proj..p3]        32MB
    u16*   Wx_bf  = (u16*)(ws + 128 * MB);     // [cvt..xproj_sk]     0.5MB
    u16*   Wdt_bf = (u16*)(ws + 128 * MB + 512 * 1024); // [cvt..dt_proj]
    u16*   yybuf  = (u16*)(ws + 128 * MB);     // [p3..out_proj]       32MB
    float* xBC    = (float*)(ws + 160 * MB);   // [combine..p3]         1MB
    u16*   dtin   = (u16*)(ws + 161 * MB);     // [combine..dt_proj]    1MB
    u16*   Wo_bf  = (u16*)(ws + 162 * MB);     // [cvt..out_proj]       4MB
    const size_t NEED = 166 * MB;
    if (ws_size < NEED) return;

    // conversions
    cvt_f32_bf16<<<8192, 256, 0, stream>>>(u, u_bf, 8388608);
    cvt_f32_bf16<<<4096, 256, 0, stream>>>(Wi, Wi_bf, 4194304);
    cvt_f32_bf16<<<2048, 256, 0, stream>>>(Wo, Wo_bf, 2097152);
    cvt_f32_bf16<<<128, 256, 0, stream>>>(Wdt, Wdt_bf, 131072);
    cvt_pad_xproj<<<1024, 256, 0, stream>>>(Wx, Wx_bf);

    // in_proj: u @ Wi^T -> xzx (cols 0..2047), xzz (cols 2048..4095)
    gemm_nt<0><<<dim3(64, 32), 256, 0, stream>>>(u_bf, Wi_bf, 8192, 4096, 1024,
                                                 nullptr, xzx, xzz, nullptr, nullptr);
    // conv + silu -> xc (token-major bf16)
    conv_silu<<<dim3(64, 32, 2), 256, 0, stream>>>(xzx, conv_w, conv_b, xc);

    // x_proj (split-K=8): partials -> combine -> dtin bf16 + xBC f32
    gemm_xproj_sk<<<dim3(64, 8), 256, 0, stream>>>(xc, Wx_bf, xpart);
    combine_xproj<<<4096, 256, 0, stream>>>(xpart, dtin, xBC);

    // dt_proj: dtb[tok,d] = bf16(softplus(dtin @ Wdt^T + dt_bias))
    gemm_nt<2><<<dim3(64, 16), 256, 0, stream>>>(dtin, Wdt_bf, 8192, 2048, 64,
                                                 nullptr, dtb, nullptr, dt_bias, nullptr);

    // chunk-parallel scan
    scan_p1<<<dim3(8, 64, 2), 256, 0, stream>>>(dtb, xc, xBC, A_log, Aagg, BaggH0);
    scan_p2<<<256, 256, 0, stream>>>(Aagg, BaggH0);
    scan_p3<<<dim3(8, 64, 2), 256, 0, stream>>>(dtb, xc, xBC, A_log, BaggH0, xzz,
                                                D_in_, yybuf);

    // out_proj: out = yy @ Wo_bf^T + D_skip*u
    gemm_nt<3><<<dim3(64, 8), 256, 0, stream>>>(yybuf, Wo_bf, 8192, 1024, 2048,
                                                out, nullptr, nullptr, D_skip, u);
}